// Round 11
// baseline (137.724 us; speedup 1.0000x reference)
//
#include <hip/hip_runtime.h>
#include <hip/hip_fp16.h>

#define BB 8
#define CC 7
#define HH 512
#define WW 512
#define HW (HH*WW)
#define NBLK 1024   // 16 x 8 x 8 hardware grid, 2 vertical 32x32 tiles per block

// Lessons encoded:
//  - NO per-block __threadfence/ticket (R2/R3: +100us L2 drain).
//  - NO same-address double atomics from all blocks (R8: removing = -24us).
//  - DPP v_add reduction (VALU pipe), not __shfl trees (LDS pipe).
//  - f16 LDS only planar stride-2 (R2: 16B-stride pack = 8-way conflict).
//  - R10: aligned exact-width loads (targets + y-halo were 16B-misaligned
//    40-col spans = 4 lines/row) + XCD swizzle so neighbor tiles share L2
//    (default round-robin puts bid, bid+1 on different XCDs).

__device__ __forceinline__ float dpp_red(float v) {
    // wave64 sum via DPP; result lands in lane 63. Validated R9.
#define STEP(ctrl) v += __int_as_float(__builtin_amdgcn_update_dpp(0, __float_as_int(v), ctrl, 0xF, 0xF, true))
    STEP(0x111); STEP(0x112); STEP(0x114); STEP(0x118);  // row_shr 1,2,4,8
    STEP(0x142); STEP(0x143);                            // row_bcast 15,31
#undef STEP
    return v;
}

__device__ __forceinline__ void softmax7x4(float4 a[7]) {
#pragma unroll
    for (int c = 0; c < 7; c++) {
        a[c].x = __expf(a[c].x); a[c].y = __expf(a[c].y);
        a[c].z = __expf(a[c].z); a[c].w = __expf(a[c].w);
    }
    float4 se = a[0];
#pragma unroll
    for (int c = 1; c < 7; c++) { se.x += a[c].x; se.y += a[c].y; se.z += a[c].z; se.w += a[c].w; }
    float ix = 1.f/se.x, iy = 1.f/se.y, iz = 1.f/se.z, iw = 1.f/se.w;
#pragma unroll
    for (int c = 0; c < 7; c++) { a[c].x *= ix; a[c].y *= iy; a[c].z *= iz; a[c].w *= iw; }
}

// plane col = global_x - gx0 + 4; cI*4 = col of first of 4 px
__device__ __forceinline__ void write_planes(unsigned short* sp, const float4 a[7], int r, int cI) {
#pragma unroll
    for (int c = 2; c < 7; c++) {
        unsigned lo = (unsigned)__half_as_ushort(__float2half_rn(a[c].x))
                    | ((unsigned)__half_as_ushort(__float2half_rn(a[c].y)) << 16);
        unsigned hi = (unsigned)__half_as_ushort(__float2half_rn(a[c].z))
                    | ((unsigned)__half_as_ushort(__float2half_rn(a[c].w)) << 16);
        *(uint2*)&sp[(c - 2) * 1360 + r * 40 + cI * 4] = make_uint2(lo, hi);
    }
}

__device__ __forceinline__ void pixel_body(const float pr[7], int t, unsigned rmv,
                                           const unsigned short* sp, const unsigned char* st,
                                           const float* sw, int cy, int cx,
                                           float& accF, float& accB,
                                           float* sumP, float* inter, float* cnt, float* num) {
    float p_t = pr[0];
#pragma unroll
    for (int c = 1; c < 7; c++) p_t = (t == c) ? pr[c] : p_t;
    float ce = sw[t] * (-__logf(p_t));
    float ptv = __expf(-ce);
    float om = 1.0f - ptv;
    accF += om * om * ce;

    float prodA = 1.0f, prodB = 1.0f;
#pragma unroll
    for (int c = 0; c < 7; c++) {
        float p = pr[c];
        bool is = (c == t);
        sumP[c] += p;
        if (is) { inter[c] += p; cnt[c] += 1.0f; }
        float arg = is ? (p + 1e-7f) : (1.0f - p + 1e-7f);
        prodA *= arg;
        prodB *= ((rmv >> c) & 1u) ? arg : 1.0f;
    }
    accB -= __logf(prodA) + 4.0f * __logf(prodB);

    if ((unsigned)(t - 2) < 5u) {
        const unsigned short* pl = sp + (t - 2) * 1360;
        int base = (cy + 1) * 40 + (cx + 4);
        int sb = (cy + 3) * 40 + (cx + 4);
        float s = 0.f;
#pragma unroll
        for (int dy = -1; dy <= 1; dy++) {
#pragma unroll
            for (int dx = -1; dx <= 1; dx++) {
                float pn = __half2float(__ushort_as_half(pl[base + dy * 40 + dx]));
                s += pn - ((st[sb + dy * 40 + dx] == t) ? 1.0f : 0.0f);
            }
        }
        float val = fabsf(s) * (1.0f / 9.0f);
#pragma unroll
        for (int q = 0; q < 5; q++) num[q] += (t == q + 2) ? val : 0.f;
    }
}

// ---- targets: 8 aligned int4/row (cols gx0..+31) + 6 scalar halo cols ----
__device__ __forceinline__ void load_tgt(int tid, int gy0, int gx0, const int* tg,
                                         int4& tv0, int4& tv1, int& tvH) {
    {   // groups 0..255: rows 0..31
        int r = tid >> 3, j4 = (tid & 7) * 4;
        int y = gy0 - 3 + r;
        size_t off = ((unsigned)y < HH) ? ((size_t)y * WW + gx0 + j4) : 0;
        tv0 = *(const int4*)(tg + off);
    }
    {   // groups 256..303: rows 32..37 (threads 0..47)
        int g = tid + 256; int gc = (g < 304) ? g : 256;
        int r = gc >> 3, j4 = (gc & 7) * 4;
        int y = gy0 - 3 + r;
        size_t off = ((g < 304) && (unsigned)y < HH) ? ((size_t)y * WW + gx0 + j4) : 0;
        tv1 = *(const int4*)(tg + off);
    }
    tvH = 255;
    if (tid < 228) {   // halo: 38 rows x 6 cols (gx0-3..-1, gx0+32..+34)
        int r = tid / 6, k = tid - r * 6;
        int c_st = (k < 3) ? (1 + k) : (33 + k);
        int x = gx0 + c_st - 4;
        int y = gy0 - 3 + r;
        if ((unsigned)y < HH && (unsigned)x < WW) tvH = tg[(size_t)y * WW + x];
    }
}

__device__ __forceinline__ void store_st(int tid, int gy0, const int4& tv0, const int4& tv1,
                                         int tvH, unsigned char* st) {
    {
        int r = tid >> 3, j4 = (tid & 7) * 4;
        int y = gy0 - 3 + r;
        unsigned w = ((unsigned)y < HH)
            ? ((unsigned)tv0.x | ((unsigned)tv0.y << 8) | ((unsigned)tv0.z << 16) | ((unsigned)tv0.w << 24))
            : 0xFFFFFFFFu;
        *(unsigned*)&st[r * 40 + 4 + j4] = w;
    }
    if (tid < 48) {
        int g = tid + 256;
        int r = g >> 3, j4 = (g & 7) * 4;
        int y = gy0 - 3 + r;
        unsigned w = ((unsigned)y < HH)
            ? ((unsigned)tv1.x | ((unsigned)tv1.y << 8) | ((unsigned)tv1.z << 16) | ((unsigned)tv1.w << 24))
            : 0xFFFFFFFFu;
        *(unsigned*)&st[r * 40 + 4 + j4] = w;
    }
    if (tid < 228) {
        int r = tid / 6, k = tid - r * 6;
        int c_st = (k < 3) ? (1 + k) : (33 + k);
        st[r * 40 + c_st] = (unsigned char)tvH;
    }
}

__device__ __forceinline__ void load_int(int tid, int gy0, int gx0, const float* lg, float4 aI[7]) {
    const int rI = 1 + (tid >> 3);
    const float* p0 = lg + (size_t)(gy0 - 1 + rI) * WW + (gx0 + (tid & 7) * 4);
#pragma unroll
    for (int c = 0; c < 7; c++) aI[c] = *(const float4*)(p0 + (size_t)c * HW);
}

// y-halo rows via aligned groups (t<16) + x-edge columns via scalars (t in [16,84))
__device__ __forceinline__ void load_halo(int tid, int gy0, int gx0, const float* lg, float4 aH[7]) {
    if (tid < 16) {
        int r = (tid >> 3) ? 33 : 0;
        int g = tid & 7;
        int y = gy0 - 1 + r;
        if ((unsigned)y < HH) {
            const float* p0 = lg + (size_t)y * WW + gx0 + g * 4;
#pragma unroll
            for (int c = 0; c < 7; c++) aH[c] = *(const float4*)(p0 + (size_t)c * HW);
        }
    } else if (tid < 84) {
        int p = tid - 16;
        int r = p >> 1;
        int x = (p & 1) ? (gx0 + 32) : (gx0 - 1);
        int y = gy0 - 1 + r;
        if ((unsigned)y < HH && (unsigned)x < WW) {
            const float* p0 = lg + (size_t)y * WW + x;
#pragma unroll
            for (int c = 0; c < 7; c++) aH[c].x = p0[(size_t)c * HW];
        }
    }
}

__device__ __forceinline__ void halo_softmax_store(int tid, int gy0, int gx0,
                                                   float4 aH[7], unsigned short* sp) {
    if (tid < 16) {
        int r = (tid >> 3) ? 33 : 0;
        int g = tid & 7;
        int y = gy0 - 1 + r;
        if ((unsigned)y < HH) {
            softmax7x4(aH);
        } else {
#pragma unroll
            for (int c = 0; c < 7; c++) aH[c] = make_float4(0.f, 0.f, 0.f, 0.f);
        }
        write_planes(sp, aH, r, 1 + g);
    } else if (tid < 84) {
        int p = tid - 16;
        int r = p >> 1;
        int side = p & 1;
        int x = side ? (gx0 + 32) : (gx0 - 1);
        int y = gy0 - 1 + r;
        int col = side ? 36 : 3;
        if ((unsigned)y < HH && (unsigned)x < WW) {
            float e[7]; float se = 0.f;
#pragma unroll
            for (int c = 0; c < 7; c++) { e[c] = __expf(aH[c].x); se += e[c]; }
            float inv = 1.0f / se;
#pragma unroll
            for (int c = 2; c < 7; c++)
                sp[(c - 2) * 1360 + r * 40 + col] = __half_as_ushort(__float2half_rn(e[c] * inv));
        } else {
#pragma unroll
            for (int c = 2; c < 7; c++) sp[(c - 2) * 1360 + r * 40 + col] = 0;
        }
    }
}

__device__ __forceinline__ void build_masks(int tid, int gy0, int gx0,
                                            const unsigned char* st, unsigned char* bm,
                                            unsigned char* hm, unsigned char* rm) {
    for (int p = tid; p < 1296; p += 256) {
        int by = p / 36, bx = p - by * 36;
        int y = gy0 - 2 + by, x = gx0 - 2 + bx;
        unsigned bits = 0;
        if ((unsigned)y < HH && (unsigned)x < WW) {
            int si = (by + 1) * 40 + (bx + 2);
            int t = st[si];
            unsigned orm = 0; int nfirst = -1, same = 1, ninb = 0;
            int n;
            n = st[si - 40]; if (n != 255) { orm |= 1u << n; if (nfirst < 0) nfirst = n; else same &= (n == nfirst); ninb++; }
            n = st[si + 40]; if (n != 255) { orm |= 1u << n; if (nfirst < 0) nfirst = n; else same &= (n == nfirst); ninb++; }
            n = st[si - 1];  if (n != 255) { orm |= 1u << n; if (nfirst < 0) nfirst = n; else same &= (n == nfirst); ninb++; }
            n = st[si + 1];  if (n != 255) { orm |= 1u << n; if (nfirst < 0) nfirst = n; else same &= (n == nfirst); ninb++; }
            unsigned andm = (ninb == 4 && same) ? (1u << nfirst) : 0u;
            unsigned cbit = 1u << t;
            bits = (orm & ~cbit) | (cbit & ~andm);
        }
        bm[p] = (unsigned char)bits;
    }
    __syncthreads();
    for (int p = tid; p < 1152; p += 256) {
        int hy = p >> 5, hx = p & 31;
        const unsigned char* r = &bm[hy * 36 + hx];
        hm[p] = (unsigned char)(r[0] | r[1] | r[2] | r[3] | r[4]);
    }
    __syncthreads();
#pragma unroll
    for (int k = 0; k < 4; k++) {
        int p = tid + k * 256;
        const unsigned char* hc2 = &hm[(p >> 5) * 32 + (p & 31)];
        rm[p] = (unsigned char)(hc2[0] | hc2[32] | hc2[64] | hc2[96] | hc2[128]);
    }
    __syncthreads();
}

__device__ __forceinline__ void phase_b(int tid, const float4 aI[7],
                                        const unsigned short* sp, const unsigned char* st,
                                        const unsigned char* rm, const float* sw,
                                        float& accF, float& accB,
                                        float* sumP, float* inter, float* cnt, float* num) {
    const int cy = tid >> 3, cxb = (tid & 7) * 4;
    unsigned rmv4 = *(const unsigned*)&rm[cy * 32 + cxb];
    unsigned t4 = *(const unsigned*)&st[(cy + 3) * 40 + cxb + 4];
    {
        float pr[7] = {aI[0].x, aI[1].x, aI[2].x, aI[3].x, aI[4].x, aI[5].x, aI[6].x};
        pixel_body(pr, (int)(t4 & 255u), rmv4 & 255u, sp, st, sw, cy, cxb + 0,
                   accF, accB, sumP, inter, cnt, num);
    }
    {
        float pr[7] = {aI[0].y, aI[1].y, aI[2].y, aI[3].y, aI[4].y, aI[5].y, aI[6].y};
        pixel_body(pr, (int)((t4 >> 8) & 255u), (rmv4 >> 8) & 255u, sp, st, sw, cy, cxb + 1,
                   accF, accB, sumP, inter, cnt, num);
    }
    {
        float pr[7] = {aI[0].z, aI[1].z, aI[2].z, aI[3].z, aI[4].z, aI[5].z, aI[6].z};
        pixel_body(pr, (int)((t4 >> 16) & 255u), (rmv4 >> 16) & 255u, sp, st, sw, cy, cxb + 2,
                   accF, accB, sumP, inter, cnt, num);
    }
    {
        float pr[7] = {aI[0].w, aI[1].w, aI[2].w, aI[3].w, aI[4].w, aI[5].w, aI[6].w};
        pixel_body(pr, (int)((t4 >> 24) & 255u), (rmv4 >> 24) & 255u, sp, st, sw, cy, cxb + 3,
                   accF, accB, sumP, inter, cnt, num);
    }
}

__global__ __launch_bounds__(256) void main_kernel(const float* __restrict__ logits,
                                                   const int* __restrict__ tgt,
                                                   const float* __restrict__ cw,
                                                   float* __restrict__ part) {
    __shared__ unsigned short sp[5 * 1360];
    __shared__ unsigned char st[40 * 38];
    __shared__ unsigned char bm[36 * 36];
    __shared__ unsigned char hm[36 * 32];
    __shared__ unsigned char rm[1024];
    __shared__ float sw[8];
    __shared__ float sred[112];

    const int tid = threadIdx.x;
    // XCD swizzle: hw dispatch order round-robins XCDs (hw%8). Give each XCD a
    // contiguous 128-tile chunk => one full image per XCD; x/y neighbor tiles
    // share that XCD's L2 for halo lines. 1024%8==0 => bijective.
    const int hw = (blockIdx.z * 8 + blockIdx.y) * 16 + blockIdx.x;
    const int lb = (hw & 7) * 128 + (hw >> 3);
    const int bx = lb & 15, byi = (lb >> 4) & 7, bz = lb >> 7;
    const int gx0 = bx * 32;
    const int gy0a = byi * 64;
    const int gy0b = byi * 64 + 32;
    if (tid < 7) sw[tid] = cw[tid];

    const float* lg = logits + (size_t)bz * CC * HW;
    const int* tg = tgt + (size_t)bz * HW;

    float accF = 0.f, accB = 0.f;
    float sumP[7] = {0,0,0,0,0,0,0};
    float inter[7] = {0,0,0,0,0,0,0};
    float cnt[7] = {0,0,0,0,0,0,0};
    float num[5] = {0,0,0,0,0};

    // ================= tile 0: issue loads =================
    int4 tv0, tv1; int tvH;
    load_tgt(tid, gy0a, gx0, tg, tv0, tv1, tvH);
    float4 aI[7];
    load_int(tid, gy0a, gx0, lg, aI);
    float4 aH[7];
    load_halo(tid, gy0a, gx0, lg, aH);

    store_st(tid, gy0a, tv0, tv1, tvH, st);
    {
        const int rI = 1 + (tid >> 3), cII = 1 + (tid & 7);
        softmax7x4(aI);
        write_planes(sp, aI, rI, cII);
    }
    halo_softmax_store(tid, gy0a, gx0, aH, sp);

    // ---- prefetch ALL of tile 1 before tile-0 compute ----
    int4 u0, u1; int uH;
    load_tgt(tid, gy0b, gx0, tg, u0, u1, uH);
    float4 aJ[7];
    load_int(tid, gy0b, gx0, lg, aJ);
    float4 aH2[7];
    load_halo(tid, gy0b, gx0, lg, aH2);

    __syncthreads();
    build_masks(tid, gy0a, gx0, st, bm, hm, rm);
    phase_b(tid, aI, sp, st, rm, sw, accF, accB, sumP, inter, cnt, num);
    __syncthreads();   // tile-0 LDS readers done

    // ================= tile 1 =================
    store_st(tid, gy0b, u0, u1, uH, st);
    {
        const int rI = 1 + (tid >> 3), cII = 1 + (tid & 7);
        softmax7x4(aJ);
        write_planes(sp, aJ, rI, cII);
    }
    halo_softmax_store(tid, gy0b, gx0, aH2, sp);

    __syncthreads();
    build_masks(tid, gy0b, gx0, st, bm, hm, rm);
    phase_b(tid, aJ, sp, st, rm, sw, accF, accB, sumP, inter, cnt, num);

    // ================= phase C: DPP reduce + partial store =================
    float vals[28];
    vals[0] = accF; vals[1] = accB;
#pragma unroll
    for (int c = 0; c < 7; c++) { vals[2+c] = sumP[c]; vals[9+c] = inter[c]; vals[16+c] = cnt[c]; }
#pragma unroll
    for (int j = 0; j < 5; j++) vals[23+j] = num[j];

    const int lane = tid & 63, wid = tid >> 6;
#pragma unroll
    for (int i = 0; i < 28; i++) {
        float v = dpp_red(vals[i]);
        if (lane == 63) sred[wid * 28 + i] = v;
    }
    __syncthreads();
    if (tid < 28) {
        float s = sred[tid] + sred[28 + tid] + sred[56 + tid] + sred[84 + tid];
        part[tid * NBLK + lb] = s;
    }
}

// ---------------------------------------------------------------------------
__global__ __launch_bounds__(1024) void reduce_kernel(const float* __restrict__ part,
                                                      float* __restrict__ out) {
    __shared__ double fin[28];
    const int tid = threadIdx.x;
    const int w = tid >> 6, lane = tid & 63;
    for (int j = w; j < 28; j += 16) {
        double s = 0.0;
#pragma unroll
        for (int k = 0; k < NBLK / 64; k++) s += (double)part[j * NBLK + lane + k * 64];
#pragma unroll
        for (int o = 32; o > 0; o >>= 1) s += __shfl_down(s, o, 64);
        if (lane == 0) fin[j] = s;
    }
    __syncthreads();
    if (tid == 0) {
        double focal = fin[0] / (double)((size_t)BB * HW);
        double bound = fin[1] / (double)((size_t)BB * CC * HW);
        double dice = 0.0;
#pragma unroll
        for (int c = 0; c < 7; c++) {
            double uni = fin[2 + c] + fin[16 + c];
            dice += 1.0 - (2.0 * fin[9 + c] + 1e-6) / (uni + 1e-6);
        }
        dice *= (1.0 / 7.0);
        double topo = 0.0;
#pragma unroll
        for (int j = 0; j < 5; j++) {
            double ms = fin[18 + j];
            double nm = fin[23 + j];
            topo += (ms >= 1.0) ? nm / fmax(ms, 1.0) : 0.0;
        }
        topo *= (1.0 / 5.0);
        out[0] = (float)(0.3 * focal + 0.3 * dice + 0.2 * bound + 0.2 * topo);
    }
}

extern "C" void kernel_launch(void* const* d_in, const int* in_sizes, int n_in,
                              void* d_out, int out_size, void* d_ws, size_t ws_size,
                              hipStream_t stream) {
    const float* logits = (const float*)d_in[0];
    const int* tgt = (const int*)d_in[1];
    const float* cw = (const float*)d_in[2];
    float* out = (float*)d_out;
    float* part = (float*)d_ws;   // 28 * 1024 floats; fully overwritten each call

    dim3 grid(WW / 32, HH / 64, BB);   // 16 x 8 x 8 = 1024 blocks, 2 tiles each
    main_kernel<<<grid, 256, 0, stream>>>(logits, tgt, cw, part);
    reduce_kernel<<<1, 1024, 0, stream>>>(part, out);
}